// Round 3
// baseline (107.217 us; speedup 1.0000x reference)
//
#include <hip/hip_runtime.h>
#include <hip/hip_bf16.h>
#include <math.h>

// NUM_MAPS=512, ZG=512, HID=96, SEQ=8, H1=3, H2=16, NPROC=8. fp32 in/out.
// R15 post-mortem: L2 warming WIN (107.9 -> 106.7). Warm blocks (kA bids
// 182..255) stream kB/kC weights into consumer XCD L2 during kA.
// R16: merge kB+kC into one 112-block kernel with a scoped producer-consumer
// handshake (NOT a grid barrier -- R14 showed cooperative grid.sync costs
// ~25us/sync on 8 XCDs). 48 producer blocks (attn1/fc1/K2/V2) do a RELEASE
// atomicAdd on flag[proc] when their ws slice is written; 64 consumer blocks
// pre-stage fc2/Wq2/Wo/De/alpha and compute Qq (needs only kA's q, so the
// old 24 Qq blocks vanish from the critical path), then spin RELAXED +
// final ACQUIRE on flag[proc]==6 before reading K2/V2. Co-residency is
// structural (112 blocks <= 256 CUs, 77KB LDS -> >=1 blk/CU), no deadlock.
// Saves one launch gap (~2.7us) + kC serial entry staging.

#define WS_ALPHA 0
#define WS_Q     512
#define WS_QKV   608      // 8*2304 -> 19040
#define WS_K2    19040    // 8*768  -> 25184
#define WS_V2    25184    // 8*768  -> 31328
#define WS_QQ    31328    // 8*96   -> 32096  (unused in R16, kept for layout)
#define WS_FLAG  32672    // 8 x u32 producer-done counters (zeroed by kA)
#define WS_SINK  32768    // warm-block DCE sink (scratch)

// ---------------------------------------------------------------------------
// KA (256 x 256):
//  blk 0..143   : QKV1. proc = blk%8 (XCD), rem = blk/8 -> (mat, six).
//  blk 144..175 : alpha. 16 m/blk, 16-way k-split, W hoisted.
//  blk 176..181 : q. 16 h/blk, 16-way k-split, W hoisted.
//  blk 182..255 : L2 warm of phase-B/C weights on XCD (blk%8). blk 182 also
//                 zeroes the handshake flags.
// ---------------------------------------------------------------------------
__global__ __launch_bounds__(256) void kA_qkv_alpha_q(
    const float* __restrict__ x, const float* __restrict__ Wa,
    const float* __restrict__ ba, const float* __restrict__ Wqr,
    const float* __restrict__ bqr, const float* __restrict__ P,
    const float* __restrict__ Wq1, const float* __restrict__ Wk1,
    const float* __restrict__ Wv1,
    const float* __restrict__ fc1w, const float* __restrict__ Wq2,
    const float* __restrict__ Wk2, const float* __restrict__ Wv2,
    const float* __restrict__ fc2w, const float* __restrict__ Wo,
    const float* __restrict__ De, const float* __restrict__ regs,
    float* __restrict__ ws)
{
    __shared__ float sK[8 * 528];   // skewed K tile (c -> c + c/32), or x
    __shared__ float sp[2048];      // partial sums
    const int blk = blockIdx.x, tid = threadIdx.x;

    if (blk < 144) {
        const int proc = blk & 7, rem = blk >> 3;       // proc -> XCD
        const int mat = rem / 6, six = rem % 6;
        const int hl = tid & 15, ks = tid >> 4;        // ks 0..15
        const int h = six * 16 + hl;
        const float* W = (mat == 0 ? Wq1 : (mat == 1 ? Wk1 : Wv1))
                         + proc * 49152 + (ks * 32) * 96 + h;
        float wreg[32];
        #pragma unroll
        for (int m2 = 0; m2 < 32; ++m2) wreg[m2] = W[m2 * 96];  // issued early
        const float4* P4 = (const float4*)(P + proc * 4096);
        for (int i = tid; i < 1024; i += 256) {
            float4 v = P4[i];
            const int c = i >> 1, off = (i & 1) * 4;
            const int cp = c + (c >> 5);
            sK[(off + 0) * 528 + cp] = v.x;
            sK[(off + 1) * 528 + cp] = v.y;
            sK[(off + 2) * 528 + cp] = v.z;
            sK[(off + 3) * 528 + cp] = v.w;
        }
        __syncthreads();
        const float* Kb = sK + ks * 33;                // skewed base
        float acc[8] = {0.f,0.f,0.f,0.f,0.f,0.f,0.f,0.f};
        #pragma unroll
        for (int m2 = 0; m2 < 32; ++m2) {
            const float w = wreg[m2];
            const float* Kc = Kb + m2;
            #pragma unroll
            for (int s = 0; s < 8; ++s) acc[s] += Kc[s * 528] * w;
        }
        float* spb = sp + ks * 128 + hl * 8;
        #pragma unroll
        for (int s = 0; s < 8; ++s) spb[s] = acc[s];
        __syncthreads();
        if (tid < 128) {            // tid = hl2*8 + s
            float a = 0.f;
            #pragma unroll
            for (int u = 0; u < 16; ++u) a += sp[u * 128 + tid];
            const int hl2 = tid >> 3, s = tid & 7;
            ws[WS_QKV + proc * 2304 + mat * 768 + s * 96 + six * 16 + hl2] = a;
        }
    } else if (blk < 176) {
        const int ml = tid & 15, ks = tid >> 4;        // 32 k each
        const int m = (blk - 144) * 16 + ml;
        const float* W = Wa + (ks * 32) * 512 + m;
        float wreg[32];
        #pragma unroll
        for (int k = 0; k < 32; ++k) wreg[k] = W[k * 512];
        for (int k = tid; k < 512; k += 256) sK[k] = x[k];
        __syncthreads();
        const float* xq = sK + ks * 32;
        float acc = 0.f;
        #pragma unroll
        for (int k = 0; k < 32; ++k) acc += xq[k] * wreg[k];
        sp[tid] = acc;
        __syncthreads();
        if (tid < 16) {
            float a = ba[(blk - 144) * 16 + tid];
            #pragma unroll
            for (int u = 0; u < 16; ++u) a += sp[u * 16 + tid];
            ws[WS_ALPHA + (blk - 144) * 16 + tid] = 1.f / (1.f + __expf(-a));
        }
    } else if (blk < 182) {
        const int hl = tid & 15, ks = tid >> 4;        // 32 k each
        const int h = (blk - 176) * 16 + hl;           // 6*16 = 96
        const float* W = Wqr + (ks * 32) * 96 + h;
        float wreg[32];
        #pragma unroll
        for (int k = 0; k < 32; ++k) wreg[k] = W[k * 96];
        for (int k = tid; k < 512; k += 256) sK[k] = x[k];
        __syncthreads();
        const float* xq = sK + ks * 32;
        float acc = 0.f;
        #pragma unroll
        for (int k = 0; k < 32; ++k) acc += xq[k] * wreg[k];
        sp[tid] = acc;
        __syncthreads();
        if (tid < 16) {
            float a = bqr[(blk - 176) * 16 + tid];
            #pragma unroll
            for (int u = 0; u < 16; ++u) a += sp[u * 16 + tid];
            ws[WS_Q + (blk - 176) * 16 + tid] = fmaxf(a, 0.f);
        }
    } else {
        // L2 warm: stream phase-B/C weights for proc = blk%8 into this XCD's
        // L2 while the real kA blocks compute. blk 182 zeroes the flags.
        const int wb = blk - 182;                      // 0..73
        if (wb == 0 && tid < 8) ((unsigned*)(ws + WS_FLAG))[tid] = 0u;
        const int proc = blk & 7;                      // consumer XCD match
        const int chunk = wb >> 3;                     // 0..9
        float acc = 0.f;
        const int base = chunk * 256 + tid;
        const int stride = 10 * 256;
        #define WARM(ptr, n4)                                            \
        {                                                                \
            const float4* p4 = (const float4*)(ptr);                     \
            for (int i = base; i < (n4); i += stride) {                  \
                float4 v = p4[i];                                        \
                acc += v.x + v.y + v.z + v.w;                            \
            }                                                            \
        }
        WARM(fc1w + proc * 9216, 2304);
        WARM(fc2w + proc * 9216, 2304);
        WARM(Wq2  + proc * 9216, 2304);
        WARM(Wk2  + proc * 9216, 2304);
        WARM(Wv2  + proc * 9216, 2304);
        WARM(Wo   + proc * 49152, 12288);
        WARM(De   + proc * 4096, 1024);
        WARM(regs + proc * 512, 128);
        #undef WARM
        if (tid == 0) ws[WS_SINK + blk] = acc;         // keep loads live
    }
}

// ---------------------------------------------------------------------------
// KBC (112 x 256): producer-consumer in one dispatch.
//  bid 0..47  : producers. proc = bid%8 (XCD), slot = bid/8 -> (mat, t).
//               attn1 -> fc1 -> K2/V2 slice -> RELEASE flag[proc]++.
//  bid 48..111: consumers. proc = bid%8, e = (bid-48)/8. Pre-stage
//               fc2/Wq2/Wo/De/alpha/q, compute Qq, spin flag[proc]==6
//               (ACQUIRE), then attn2 -> fc2 -> Wo -> epilogue.
// ---------------------------------------------------------------------------
__global__ __launch_bounds__(256) void kBC_fused(
    const float* __restrict__ fc1w, const float* __restrict__ Wk2,
    const float* __restrict__ Wv2, const float* __restrict__ Wq2,
    const float* __restrict__ gate, const float* __restrict__ De,
    const float* __restrict__ regs, const float* __restrict__ fc2w,
    const float* __restrict__ Wo, float* __restrict__ ws,
    float* __restrict__ out)
{
    __shared__ float lds[19208];          // union: producer 16320 / consumer 19208
    const int bid = blockIdx.x, tid = threadIdx.x;
    const float rs = 0.10206207261596577f;  // 1/sqrt(96)

    if (bid < 48) {
        // ---------------- producer: attn1 -> fc1 -> K2/V2 ----------------
        const int proc = bid & 7, slot = bid >> 3;      // proc -> XCD
        const int mat = slot / 3, t = slot % 3;
        float* sWf1 = lds;                // 9216, fc1 row-major [i][j]
        float* sWkv = lds + 9216;         // 3072, Wk2/Wv2 column slice [i][jl]
        float* sQk  = lds + 12288;        // 768
        float* sKk  = lds + 13056;        // 768
        float* sVv  = lds + 13824;        // 768
        float* sH   = lds + 14592;        // 768
        float* sH2  = lds + 15360;        // 768
        float* sS   = lds + 16128;        // 192 -> 16320

        {   // entry burst (L2-warmed by kA)
            const float4* F4 = (const float4*)fc1w + proc * 2304;
            float4* D4 = (float4*)sWf1;
            #pragma unroll
            for (int r = 0; r < 9; ++r) D4[tid + 256 * r] = F4[tid + 256 * r];
            const float4* KV4 = (const float4*)(mat ? Wv2 : Wk2);
            float4* E4 = (float4*)sWkv;
            #pragma unroll
            for (int r = 0; r < 3; ++r) {
                const int idx = tid + 256 * r;          // 768 float4
                const int row = idx >> 3, q4 = idx & 7;
                E4[row * 8 + q4] = KV4[proc * 2304 + row * 24 + t * 8 + q4];
            }
        }
        const float* qkv = ws + WS_QKV + proc * 2304;
        for (int i = tid; i < 768; i += 256) {
            sQk[i] = qkv[i]; sKk[i] = qkv[768 + i]; sVv[i] = qkv[1536 + i];
        }
        __syncthreads();

        if (tid < 192) {       // attn1 logits (h0, si, sk)
            const int h0 = tid / 64, r64 = tid % 64, si = r64 / 8, sk = r64 % 8;
            float acc = 0.f;
            #pragma unroll
            for (int d = 0; d < 32; ++d)
                acc += sQk[si * 96 + h0 * 32 + d] * sKk[sk * 96 + h0 * 32 + d];
            sS[tid] = acc * rs;
        }
        __syncthreads();
        if (tid < 24) {        // softmax row -> probs in place
            float* row = sS + tid * 8;
            float mx = row[0];
            #pragma unroll
            for (int k = 1; k < 8; ++k) mx = fmaxf(mx, row[k]);
            float e[8], sum = 0.f;
            #pragma unroll
            for (int k = 0; k < 8; ++k) { e[k] = __expf(row[k] - mx); sum += e[k]; }
            const float inv = 1.f / sum;
            #pragma unroll
            for (int k = 0; k < 8; ++k) row[k] = e[k] * inv;
        }
        __syncthreads();
        if (tid < 192) {       // AV + residual (h0, si, dq): 4 d's each
            const int h0 = tid / 64, r64 = tid % 64, si = r64 / 8, dq = r64 % 8;
            const float* e = sS + h0 * 64 + si * 8;
            float o0 = 0.f, o1 = 0.f, o2 = 0.f, o3 = 0.f;
            #pragma unroll
            for (int k = 0; k < 8; ++k) {
                const float ek = e[k];
                const float* v = sVv + k * 96 + h0 * 32 + dq * 4;
                o0 += ek*v[0]; o1 += ek*v[1]; o2 += ek*v[2]; o3 += ek*v[3];
            }
            const int base = si * 96 + h0 * 32 + dq * 4;
            sH[base+0] = sQk[base+0] + o0;  sH[base+1] = sQk[base+1] + o1;
            sH[base+2] = sQk[base+2] + o2;  sH[base+3] = sQk[base+3] + o3;
        }
        __syncthreads();
        // fc1 from LDS (full, redundant): 3 outputs/thread
        #pragma unroll
        for (int r = 0; r < 3; ++r) {
            const int idx = tid + 256 * r, s = idx / 96, j = idx % 96;
            const float* Hs = sH + s * 96;
            float acc = 0.f;
            #pragma unroll
            for (int i = 0; i < 96; ++i) acc += Hs[i] * sWf1[i * 96 + j];
            sH2[idx] = sH[idx] + fmaxf(acc, 0.f);
        }
        __syncthreads();
        // K2/V2 slice from LDS: (s, jl)
        const int s = tid >> 5, jl = tid & 31, j = t * 32 + jl;
        const float* Hs = sH2 + s * 96;
        float acc = 0.f;
        #pragma unroll
        for (int i = 0; i < 96; ++i) acc += Hs[i] * sWkv[i * 32 + jl];
        ws[(mat ? WS_V2 : WS_K2) + proc * 768 + s * 96 + j] = acc;
        __syncthreads();       // drains vmcnt: all block stores at L2
        if (tid == 0)
            __hip_atomic_fetch_add((unsigned*)(ws + WS_FLAG) + proc, 1u,
                                   __ATOMIC_RELEASE, __HIP_MEMORY_SCOPE_AGENT);
    } else {
        // ---------------- consumer: prestage + Qq, wait, attn2 ----------------
        const int cid = bid - 48, proc = bid & 7, e = cid >> 3;
        float* sWf2 = lds;                // 9216 (persistent)
        float* sWq2 = lds + 9216;         // 9216 during prestage...
        float* sK2  = lds + 9216;         // ...then overlaid by K2 (768)
        float* sV2  = lds + 9984;         // and V2 (768)
        float* sQq  = lds + 18432;        // 96
        float* sq   = lds + 18528;        // 96
        float* sO   = lds + 18624;        // 96
        float* sOf  = lds + 18720;        // 96
        float* sE2  = lds + 18816;        // 128
        float* sg   = lds + 18944;        // 8
        float* sp   = lds + 18952;        // 256 -> 19208

        // ---- prestage (all from kA-warmed L2; no kB dependency) ----
        {
            const float4* F4 = (const float4*)fc2w + proc * 2304;
            float4* D4 = (float4*)sWf2;
            #pragma unroll
            for (int r = 0; r < 9; ++r) D4[tid + 256 * r] = F4[tid + 256 * r];
            const float4* Q4 = (const float4*)Wq2 + proc * 2304;
            float4* D5 = (float4*)sWq2;
            #pragma unroll
            for (int r = 0; r < 9; ++r) D5[tid + 256 * r] = Q4[tid + 256 * r];
        }
        const int ml = tid & 63, ksv = tid >> 6;
        const int m = 64 * e + ml;
        float wor[24];                    // Wo column slice, regs
        {
            const float* Wop = Wo + proc * 49152 + m;
            #pragma unroll
            for (int i = 0; i < 24; ++i) wor[i] = Wop[(24 * ksv + i) * 512];
        }
        const float4* Dp4 = (const float4*)(De + proc * 4096 + m * 8);
        const float4 d0 = Dp4[0], d1 = Dp4[1];
        const float av = ws[WS_ALPHA + m];       // kA output (prior kernel)
        const float rg = regs[proc * 512 + m];
        if (tid < 96) sq[tid] = ws[WS_Q + tid];  // kA output
        else if (tid >= 96 && tid < 104) sg[tid - 96] = gate[tid - 96];
        __syncthreads();

        // ---- Qq = q @ Wq2[proc] (2-way k-split over 192 threads) ----
        if (tid < 192) {
            const int j = tid % 96, k2 = tid / 96;
            const float* qs = sq + k2 * 48;
            float acc = 0.f;
            #pragma unroll
            for (int i = 0; i < 48; ++i) acc += qs[i] * sWq2[(k2 * 48 + i) * 96 + j];
            sp[tid] = acc;
        }
        __syncthreads();
        if (tid < 96) sQq[tid] = sp[tid] + sp[96 + tid];

        // ---- handshake: wait for this proc's 6 producers ----
        if (tid == 0) {
            unsigned* fp = (unsigned*)(ws + WS_FLAG) + proc;
            while (__hip_atomic_load(fp, __ATOMIC_RELAXED,
                                     __HIP_MEMORY_SCOPE_AGENT) < 6u)
                __builtin_amdgcn_s_sleep(4);
            (void)__hip_atomic_load(fp, __ATOMIC_ACQUIRE,
                                    __HIP_MEMORY_SCOPE_AGENT);
        }
        __syncthreads();

        // ---- K2/V2 now visible (overlay Wq2 region; Wq2 done) ----
        for (int i = tid; i < 768; i += 256) {
            sK2[i] = ws[WS_K2 + proc * 768 + i];
            sV2[i] = ws[WS_V2 + proc * 768 + i];
        }
        __syncthreads();

        // attn2 probs: 16 heads, d=6, 1 query row
        if (tid < 16) {
            const int h0 = tid;
            float lg[8], mx = -1e30f;
            #pragma unroll
            for (int k = 0; k < 8; ++k) {
                float acc = 0.f;
                #pragma unroll
                for (int d = 0; d < 6; ++d)
                    acc += sQq[h0 * 6 + d] * sK2[k * 96 + h0 * 6 + d];
                lg[k] = acc * rs; mx = fmaxf(mx, lg[k]);
            }
            float ex[8], sum = 0.f;
            #pragma unroll
            for (int k = 0; k < 8; ++k) { ex[k] = __expf(lg[k] - mx); sum += ex[k]; }
            const float inv = 1.f / sum;
            #pragma unroll
            for (int k = 0; k < 8; ++k) sE2[h0 * 8 + k] = ex[k] * inv;
        }
        __syncthreads();
        if (tid < 96) {           // AV + residual
            const int h0 = tid / 6;
            float o = 0.f;
            #pragma unroll
            for (int k = 0; k < 8; ++k) o += sE2[h0 * 8 + k] * sV2[k * 96 + tid];
            sO[tid] = sQq[tid] + o;
        }
        __syncthreads();
        if (tid < 192) {          // fc2 from LDS, 2-way k-split
            const int j = tid % 96, k2 = tid / 96;
            const float* Os = sO + k2 * 48;
            float acc = 0.f;
            #pragma unroll
            for (int i = 0; i < 48; ++i) acc += Os[i] * sWf2[(k2 * 48 + i) * 96 + j];
            sp[tid] = acc;
        }
        __syncthreads();
        if (tid < 96) sOf[tid] = sO[tid] + fmaxf(sp[tid] + sp[96 + tid], 0.f);
        __syncthreads();

        // Wo slice from regs: 64 maps, 4-way k-split
        float acc = 0.f;
        #pragma unroll
        for (int i = 0; i < 24; ++i) acc += sOf[24 * ksv + i] * wor[i];
        sp[tid] = acc;
        __syncthreads();
        if (ksv == 0) {
            const float tr = sp[ml] + sp[ml + 64] + sp[ml + 128] + sp[ml + 192];
            const float de = d0.x * sg[0] + d0.y * sg[1] + d0.z * sg[2] + d0.w * sg[3]
                           + d1.x * sg[4] + d1.y * sg[5] + d1.z * sg[6] + d1.w * sg[7];
            const float mix = av * tr + (1.f - av) * de;
            const int pt = proc & 3;                 // gamma gets +1, beta not
            const float off = (pt == 0 || pt == 2) ? 1.f : 0.f;
            out[proc * 512 + m] = mix * rg + off;
        }
    }
}

extern "C" void kernel_launch(void* const* d_in, const int* in_sizes, int n_in,
                              void* d_out, int out_size, void* d_ws, size_t ws_size,
                              hipStream_t stream)
{
    const float* gate = (const float*)d_in[0];
    const float* x    = (const float*)d_in[1];
    const float* Wa   = (const float*)d_in[2];
    const float* ba   = (const float*)d_in[3];
    const float* Wqr  = (const float*)d_in[4];
    const float* bqr  = (const float*)d_in[5];
    const float* P    = (const float*)d_in[6];
    const float* De   = (const float*)d_in[7];
    const float* regs = (const float*)d_in[8];
    const float* Wq1  = (const float*)d_in[9];
    const float* Wk1  = (const float*)d_in[10];
    const float* Wv1  = (const float*)d_in[11];
    const float* fc1  = (const float*)d_in[12];
    const float* Wq2  = (const float*)d_in[13];
    const float* Wk2  = (const float*)d_in[14];
    const float* Wv2  = (const float*)d_in[15];
    const float* fc2  = (const float*)d_in[16];
    const float* Wo   = (const float*)d_in[17];
    float* ws = (float*)d_ws;

    hipLaunchKernelGGL(kA_qkv_alpha_q, dim3(256), dim3(256), 0, stream,
                       x, Wa, ba, Wqr, bqr, P, Wq1, Wk1, Wv1,
                       fc1, Wq2, Wk2, Wv2, fc2, Wo, De, regs, ws);
    hipLaunchKernelGGL(kBC_fused, dim3(112), dim3(256), 0, stream,
                       fc1, Wk2, Wv2, Wq2, gate, De, regs, fc2, Wo,
                       ws, (float*)d_out);
}